// Round 1
// baseline (267.121 us; speedup 1.0000x reference)
//
#include <hip/hip_runtime.h>
#include <hip/hip_bf16.h>

// ProfileHMM forward on MI355X.
// Reformulation: trans-matrix is (diag-direct + rank-1-in-log-space chain);
// each scan step becomes a weighted prefix recurrence R[m+1]=w[m]R[m]+E'[m]
// over 385 positions instead of a (769x769) matmul. One wave per batch
// element, all state in registers, shuffle-based weighted scan.

#define NEGC (-1.0e32f)

// d_ws float offsets
#define OFF_AEM  0        // E' coeff for pm[j-1]                (385)
#define OFF_AEI  385      // E' coeff for pi[j]                  (385)
#define OFF_AW   770      // recurrence weight exp(d2[j])        (385)
#define OFF_BDMA 1155     // pm_new[j] += pm[j-1]*..             (385)
#define OFF_BDMB 1540     // pm_new[j] += pi[j]*..               (385)
#define OFF_BGM  1925     // pm_new[j] += ..*R[j]                (385)
#define OFF_BDIA 2310     // pi_new[j] += pm[j-1]*..             (385)
#define OFF_BDIB 2695     // pi_new[j] += pi[j]*..               (385)
#define OFF_BGI  3080     // pi_new[j] += ..*R[j]                (385)
#define OFF_P0M  3465     // initial pm (385, [384]=0)
#define OFF_P0I  3850     // initial pi (385)
#define OFF_WOM  4235     // emission weights, match rows 384*21
#define OFF_WOI  (4235+8064) // emission weights, insert rows 385*21
// total = 20384 floats = 81.5 KB

__global__ void hmm_setup(const float* __restrict__ ps, const float* __restrict__ iseq,
                          const float* __restrict__ rr, const float* __restrict__ uu,
                          float* __restrict__ ws)
{
    const int tid = threadIdx.x;
    const int nth = blockDim.x;   // 512
    __shared__ float rn[2304];    // log-softmaxed insert_logits (m,j,c) flat
    __shared__ float un[2304];    // log-softmaxed delete_logits
    __shared__ float d2s[384];
    __shared__ float ews[385];    // exp(d2)
    __shared__ float etmm[385];   // exp(t_match) per target m' (0 at 384)
    __shared__ float etii[385];   // exp(t_ins)  per target m' (1 at 384)
    __shared__ float Cs[385];     // cumsum of d2
    __shared__ float qa[385];     // q[s] = sum_{m'>s} exp(C[m']-C[s+1]+t_term)
    __shared__ float rawv[769];
    __shared__ float red[512];

    // normalize r,u rows (2-element log-softmax)
    for (int row = tid; row < 1152; row += nth) {
        float a = rr[row*2], b = rr[row*2+1];
        float mx = fmaxf(a, b);
        float l = mx + logf(expf(a-mx) + expf(b-mx));
        rn[row*2] = a - l; rn[row*2+1] = b - l;
        a = uu[row*2]; b = uu[row*2+1];
        mx = fmaxf(a, b);
        l = mx + logf(expf(a-mx) + expf(b-mx));
        un[row*2] = a - l; un[row*2+1] = b - l;
    }
    __syncthreads();
    for (int m = tid; m < 384; m += nth) {
        float d = rn[(m*3+2)*2+0] + un[(m*3+2)*2+1];
        d2s[m] = d;
        ews[m] = expf(d);
        etmm[m] = expf(rn[(m*3+2)*2+0] + un[(m*3+2)*2+0]);
        etii[m] = expf(rn[(m*3+2)*2+1]);
    }
    if (tid == 0) { ews[384] = 0.f; etmm[384] = 0.f; etii[384] = 1.f; }
    __syncthreads();
    if (tid == 0) {
        Cs[0] = 0.f;
        for (int j = 1; j <= 384; ++j) Cs[j] = Cs[j-1] + d2s[j-1];
        qa[384] = 0.f;
        for (int s = 384; s >= 1; --s) {
            float v = etii[s] + etmm[s];           // etmm[384]==0 handles s=384
            if (s <= 383) v += qa[s] * ews[s];
            qa[s-1] = v;
        }
    }
    __syncthreads();
    // per-source-state row normalization + coefficient arrays
    for (int k = tid; k < 769; k += nth) {
        int g = (k < 384) ? 0 : 1;
        int m = (k < 384) ? k : (k - 384);
        int s = m + 1 - g;
        float ss, sd, sm, si;
        if (s <= 383) {
            int base = (s*3 + g)*2;
            ss = rn[base+0]; si = rn[base+1];
            sm = un[base+0]; sd = un[base+1];
        } else { ss = NEGC; si = 0.f; sm = 0.f; sd = NEGC; }   // pad row M
        float d0 = (s <= 383) ? (ss + sm) : NEGC;  // direct -> match target m'=s
        float d1 = si;                             // direct -> insert target m'=s
        float q = qa[s];
        float lq = (q > 0.f) ? logf(q) : -1.0e30f;
        float ch = ss + sd + lq;                   // logsumexp of all chain entries
        float mx = fmaxf(fmaxf(d0, d1), ch);
        float Z = mx + logf(expf(d0-mx) + expf(d1-mx) + expf(ch-mx));
        float we = expf(ss + sd - Z);
        float w0 = expf(d0 - Z);
        float w1 = expf(d1 - Z);
        if (g == 0) { // match source m, decision slot s=m+1
            ws[OFF_AEM + s] = we;
            ws[OFF_BDMA + s] = w0;
            ws[OFF_BDIA + s] = w1;
        } else {      // insert source m, slot s=m
            ws[OFF_AEI + s] = we;
            ws[OFF_BDMB + s] = w0;
            ws[OFF_BDIB + s] = w1;
        }
    }
    for (int j = tid; j < 385; j += nth) {
        ws[OFF_AW  + j] = (j <= 383) ? ews[j] : 1.0f;
        ws[OFF_BGM + j] = etmm[j];
        ws[OFF_BGI + j] = etii[j];
    }
    if (tid == 0) { ws[OFF_AEM+0] = 0.f; ws[OFF_BDMA+0] = 0.f; ws[OFF_BDIA+0] = 0.f; }
    __syncthreads();
    // initial vector (raw, then global logsumexp-normalized)
    float r000 = rn[0], r001 = rn[1];
    float u000 = un[0], u001 = un[1];
    for (int k = tid; k < 769; k += nth) {
        int g = (k < 384) ? 0 : 1;
        int m = (k < 384) ? k : (k - 384);
        float v;
        if (m == 0) v = g ? r001 : (r000 + u000);
        else {
            float tt = g ? ((m <= 383) ? rn[(m*3+2)*2+1] : 0.f)
                         : (rn[(m*3+2)*2+0] + un[(m*3+2)*2+0]);
            v = r000 + u001 - Cs[1] + Cs[m] + tt;
        }
        rawv[k] = v;
    }
    __syncthreads();
    float lmax = -3.0e38f;
    for (int k = tid; k < 769; k += nth) lmax = fmaxf(lmax, rawv[k]);
    red[tid] = lmax; __syncthreads();
    for (int off = 256; off > 0; off >>= 1) {
        if (tid < off) red[tid] = fmaxf(red[tid], red[tid+off]);
        __syncthreads();
    }
    float gmax = red[0]; __syncthreads();
    float lsum = 0.f;
    for (int k = tid; k < 769; k += nth) lsum += expf(rawv[k] - gmax);
    red[tid] = lsum; __syncthreads();
    for (int off = 256; off > 0; off >>= 1) {
        if (tid < off) red[tid] += red[tid+off];
        __syncthreads();
    }
    float lse = gmax + logf(red[0]); __syncthreads();
    for (int k = tid; k < 769; k += nth) {
        float p = expf(rawv[k] - lse);
        if (k < 384) ws[OFF_P0M + k] = p;
        else ws[OFF_P0I + (k-384)] = p;
    }
    if (tid == 0) ws[OFF_P0M + 384] = 0.f;
    // emission probability weights exp(log_softmax(obs_row))
    for (int row = tid; row < 769; row += nth) {
        const float* src = (row < 384) ? (ps + row*21) : (iseq + (row-384)*21);
        float mx = -3.0e38f;
        for (int a = 0; a < 21; ++a) mx = fmaxf(mx, src[a]);
        float sm2 = 0.f;
        for (int a = 0; a < 21; ++a) sm2 += expf(src[a]-mx);
        float inv = 1.0f / sm2;
        float* dst = (row < 384) ? (ws + OFF_WOM + row*21) : (ws + OFF_WOI + (row-384)*21);
        for (int a = 0; a < 21; ++a) dst[a] = expf(src[a]-mx) * inv;
    }
}

__global__ __launch_bounds__(64, 1) void hmm_scan(const float* __restrict__ seq,
                                                  const float* __restrict__ ws,
                                                  const float* __restrict__ lscale,
                                                  float* __restrict__ out)
{
    const int b = blockIdx.x;
    const int lane = threadIdx.x;
    __shared__ int letters[256];
    const float* sb = seq + (size_t)b * 256 * 21;
    for (int c = 0; c < 4; ++c) {
        int t = c*64 + lane;
        const float* p = sb + t*21;
        float s = 0.f, wsum = 0.f;
        #pragma unroll
        for (int a = 0; a < 21; ++a) { float v = p[a]; s += v; wsum += v * (float)a; }
        letters[t] = (s > 0.5f) ? (int)(wsum + 0.5f) : -1;
    }
    __syncthreads();

    float c_em[7], c_ei[7], c_w[7], c_dma[7], c_dmb[7], c_gm[7], c_dia[7], c_dib[7], c_gi[7];
    float pm[7], pi[7];
    int offm[7], offi[7];
    #pragma unroll
    for (int i = 0; i < 7; ++i) {
        int j = lane*7 + i;
        bool v = (j < 385);
        int js = v ? j : 384;
        c_em[i]  = v ? ws[OFF_AEM  + j] : 0.f;
        c_ei[i]  = v ? ws[OFF_AEI  + j] : 0.f;
        c_w[i]   = v ? ws[OFF_AW   + j] : 1.f;
        c_dma[i] = v ? ws[OFF_BDMA + j] : 0.f;
        c_dmb[i] = v ? ws[OFF_BDMB + j] : 0.f;
        c_gm[i]  = v ? ws[OFF_BGM  + j] : 0.f;
        c_dia[i] = v ? ws[OFF_BDIA + j] : 0.f;
        c_dib[i] = v ? ws[OFF_BDIB + j] : 0.f;
        c_gi[i]  = v ? ws[OFF_BGI  + j] : 0.f;
        pm[i] = v ? ws[OFF_P0M + j] : 0.f;
        pi[i] = v ? ws[OFF_P0I + j] : 0.f;
        int jm = (js > 383) ? 383 : js;
        offm[i] = jm * 21;
        offi[i] = js * 21;
    }
    const float* wom = ws + OFF_WOM;
    const float* woi = ws + OFF_WOI;

    { // t = 0 emission
        int lm = letters[0];
        if (lm >= 0) {
            #pragma unroll
            for (int i = 0; i < 7; ++i) { pm[i] *= wom[offm[i] + lm]; pi[i] *= woi[offi[i] + lm]; }
        }
    }
    float logoff = 0.f;
    { // initial renorm (p0 can be small)
        float mx = 0.f;
        #pragma unroll
        for (int i = 0; i < 7; ++i) mx = fmaxf(mx, fmaxf(pm[i], pi[i]));
        #pragma unroll
        for (int d = 1; d < 64; d <<= 1) mx = fmaxf(mx, __shfl_xor(mx, d));
        if (mx > 0.f) {
            float sc = 1.0f / mx;
            logoff += logf(mx);
            #pragma unroll
            for (int i = 0; i < 7; ++i) { pm[i] *= sc; pi[i] *= sc; }
        }
    }

    // data-independent shuffle-scan multipliers (A-components are constants)
    float Ar[6];
    float aseg = c_w[0]*c_w[1]*c_w[2]*c_w[3]*c_w[4]*c_w[5]*c_w[6];
    #pragma unroll
    for (int r2 = 0; r2 < 6; ++r2) {
        int d = 1 << r2;
        Ar[r2] = aseg;
        float lo = __shfl_up(aseg, (unsigned)d);
        if (lane >= d) aseg *= lo;
    }

    for (int t = 1; t < 256; ++t) {
        int lm = letters[t];
        bool has = (lm >= 0);
        float em0[7], em1[7];
        if (has) {
            #pragma unroll
            for (int i = 0; i < 7; ++i) { em0[i] = wom[offm[i] + lm]; em1[i] = woi[offi[i] + lm]; }
        }
        float pmprev = __shfl_up(pm[6], 1u);
        if (lane == 0) pmprev = 0.f;
        float aprev[7], Ei[7];
        #pragma unroll
        for (int i = 0; i < 7; ++i) aprev[i] = (i == 0) ? pmprev : pm[i-1];
        float bb = 0.f;
        #pragma unroll
        for (int i = 0; i < 7; ++i) { Ei[i] = aprev[i]*c_em[i] + pi[i]*c_ei[i]; bb = c_w[i]*bb + Ei[i]; }
        // weighted wave scan (6 rounds); multiplicative part precomputed in Ar
        #pragma unroll
        for (int r2 = 0; r2 < 6; ++r2) {
            int d = 1 << r2;
            float lo = __shfl_up(bb, (unsigned)d);
            if (lane >= d) bb = Ar[r2]*lo + bb;
        }
        float bx = __shfl_up(bb, 1u);
        float R = (lane == 0) ? 0.f : bx;
        #pragma unroll
        for (int i = 0; i < 7; ++i) {
            float npm = aprev[i]*c_dma[i] + pi[i]*c_dmb[i] + c_gm[i]*R;
            float npi = aprev[i]*c_dia[i] + pi[i]*c_dib[i] + c_gi[i]*R;
            R = c_w[i]*R + Ei[i];
            if (has) { npm *= em0[i]; npi *= em1[i]; }
            pm[i] = npm; pi[i] = npi;
        }
        if ((t & 3) == 0) {
            float mx = 0.f;
            #pragma unroll
            for (int i = 0; i < 7; ++i) mx = fmaxf(mx, fmaxf(pm[i], pi[i]));
            #pragma unroll
            for (int d = 1; d < 64; d <<= 1) mx = fmaxf(mx, __shfl_xor(mx, d));
            if (mx > 0.f) {
                float sc = 1.0f / mx;
                logoff += logf(mx);
                #pragma unroll
                for (int i = 0; i < 7; ++i) { pm[i] *= sc; pi[i] *= sc; }
            }
        }
    }
    float s = 0.f;
    #pragma unroll
    for (int i = 0; i < 7; ++i) s += pm[i] + pi[i];
    #pragma unroll
    for (int d = 1; d < 64; d <<= 1) s += __shfl_xor(s, d);
    if (lane == 0) out[b] = lscale[0] * (logf(s) + logoff);
}

extern "C" void kernel_launch(void* const* d_in, const int* in_sizes, int n_in,
                              void* d_out, int out_size, void* d_ws, size_t ws_size,
                              hipStream_t stream)
{
    const float* ps   = (const float*)d_in[0];  // precursor_seq (384,21)
    const float* iseq = (const float*)d_in[1];  // insert_seq (385,21)
    const float* ins  = (const float*)d_in[2];  // insert (384,3,2)
    const float* del  = (const float*)d_in[3];  // delete (384,3,2)
    const float* seq  = (const float*)d_in[4];  // seq_data (64,256,21)
    const float* lsc  = (const float*)d_in[5];  // local_scale (1,)
    float* ws = (float*)d_ws;
    float* out = (float*)d_out;
    hmm_setup<<<1, 512, 0, stream>>>(ps, iseq, ins, del, ws);
    hmm_scan<<<64, 64, 0, stream>>>(seq, ws, lsc, out);
}

// Round 2
// 154.929 us; speedup vs baseline: 1.7241x; 1.7241x over previous
//
#include <hip/hip_runtime.h>
#include <hip/hip_bf16.h>

// ProfileHMM forward on MI355X.
// Reformulation: trans-matrix = diag-direct + rank-1-in-log-space delete chain;
// each scan step is a weighted prefix recurrence over 385 positions.
// One wave per batch element; cross-lane scan via DPP (row_shr + row_bcast),
// in-lane Kogge-Stone tree; emissions prefetched 2 steps ahead from
// lane-padded transposed tables.

#define NEGC (-1.0e32f)

// d_ws float offsets
#define OFF_AEM  0
#define OFF_AEI  385
#define OFF_AW   770
#define OFF_BDMA 1155
#define OFF_BDMB 1540
#define OFF_BGM  1925
#define OFF_BDIA 2310
#define OFF_BDIB 2695
#define OFF_BGI  3080
#define OFF_P0M  3465
#define OFF_P0I  3850
#define OFF_WTM  4352              // 16B-aligned; [letter][lane][8] = 21*512
#define OFF_WTI  (4352 + 10752)    // 15104, 16B-aligned
// total 25856 floats = 101 KB of d_ws

template<int CTRL>
__device__ __forceinline__ float fdpp(float x) {
    union { float f; int i; } u, r;
    u.f = x;
    r.i = __builtin_amdgcn_update_dpp(0, u.i, CTRL, 0xF, 0xF, true);
    return r.f;
}
// whole-wave shift right by 1 lane (lane0 <- 0), composed from row_shr:1 +
// row_bcast15 (lane15->row1, lane31->row2, lane47->row3; rows get 0-fill else)
__device__ __forceinline__ float wshr1(float x, int lane) {
    float a = fdpp<0x111>(x);   // row_shr:1
    float b = fdpp<0x142>(x);   // row_bcast15
    return ((lane & 15) == 0) ? b : a;
}

__global__ void hmm_setup(const float* __restrict__ ps, const float* __restrict__ iseq,
                          const float* __restrict__ rr, const float* __restrict__ uu,
                          float* __restrict__ ws)
{
    const int tid = threadIdx.x;
    const int nth = blockDim.x;   // 512
    __shared__ float rn[2304];
    __shared__ float un[2304];
    __shared__ float d2s[384];
    __shared__ float ews[385];
    __shared__ float etmm[385];
    __shared__ float etii[385];
    __shared__ float Cs[385];
    __shared__ float qa[385];
    __shared__ float rawv[769];
    __shared__ float red[16];

    for (int row = tid; row < 1152; row += nth) {
        float a = rr[row*2], b = rr[row*2+1];
        float mx = fmaxf(a, b);
        float l = mx + logf(expf(a-mx) + expf(b-mx));
        rn[row*2] = a - l; rn[row*2+1] = b - l;
        a = uu[row*2]; b = uu[row*2+1];
        mx = fmaxf(a, b);
        l = mx + logf(expf(a-mx) + expf(b-mx));
        un[row*2] = a - l; un[row*2+1] = b - l;
    }
    __syncthreads();
    for (int m = tid; m < 384; m += nth) {
        float d = rn[(m*3+2)*2+0] + un[(m*3+2)*2+1];
        d2s[m] = d;
        ews[m] = expf(d);
        etmm[m] = expf(rn[(m*3+2)*2+0] + un[(m*3+2)*2+0]);
        etii[m] = expf(rn[(m*3+2)*2+1]);
    }
    if (tid == 0) { ews[384] = 0.f; etmm[384] = 0.f; etii[384] = 1.f; }
    __syncthreads();
    // wave 0: additive prefix scan for Cs; wave 1: weighted reverse scan for qa
    if (tid < 64) {
        int lane = tid;
        float incl[6]; float z = 0.f;
        #pragma unroll
        for (int i = 0; i < 6; ++i) { z += d2s[lane*6+i]; incl[i] = z; }
        float tot = z;
        #pragma unroll
        for (int d = 1; d < 64; d <<= 1) { float q = __shfl_up(tot, d); if (lane >= d) tot += q; }
        float excl = __shfl_up(tot, 1); if (lane == 0) excl = 0.f;
        #pragma unroll
        for (int i = 0; i < 6; ++i) Cs[lane*6+i+1] = excl + incl[i];
        if (lane == 0) Cs[0] = 0.f;
    } else if (tid < 128) {
        int lane = tid - 64;
        float wv[6], xv[6], incl[6];
        #pragma unroll
        for (int i = 0; i < 6; ++i) {
            int s = 384 - (lane*6 + i);
            wv[i] = ews[s]; xv[i] = etii[s] + etmm[s];
        }
        float z = 0.f, Wl = 1.f;
        #pragma unroll
        for (int i = 0; i < 6; ++i) { z = fmaf(wv[i], z, xv[i]); incl[i] = z; Wl *= wv[i]; }
        float val = z, wt = Wl;
        #pragma unroll
        for (int d = 1; d < 64; d <<= 1) {
            float pv = __shfl_up(val, d); float pw_ = __shfl_up(wt, d);
            if (lane >= d) { val = fmaf(wt, pv, val); wt *= pw_; }
        }
        float excl = __shfl_up(val, 1); if (lane == 0) excl = 0.f;
        float pp = 1.f;
        #pragma unroll
        for (int i = 0; i < 6; ++i) {
            pp *= wv[i];
            float zf = fmaf(excl, pp, incl[i]);
            qa[383 - (lane*6 + i)] = zf;
        }
        if (lane == 0) qa[384] = 0.f;
    }
    __syncthreads();
    // per-source-state row normalization + coefficient arrays
    for (int k = tid; k < 769; k += nth) {
        int g = (k < 384) ? 0 : 1;
        int m = (k < 384) ? k : (k - 384);
        int s = m + 1 - g;
        float ss, sd, sm, si;
        if (s <= 383) {
            int base = (s*3 + g)*2;
            ss = rn[base+0]; si = rn[base+1];
            sm = un[base+0]; sd = un[base+1];
        } else { ss = NEGC; si = 0.f; sm = 0.f; sd = NEGC; }
        float d0 = (s <= 383) ? (ss + sm) : NEGC;
        float d1 = si;
        float q = qa[s];
        float lq = (q > 0.f) ? logf(q) : -1.0e30f;
        float ch = ss + sd + lq;
        float mx = fmaxf(fmaxf(d0, d1), ch);
        float Z = mx + logf(expf(d0-mx) + expf(d1-mx) + expf(ch-mx));
        float we = expf(ss + sd - Z);
        float w0 = expf(d0 - Z);
        float w1 = expf(d1 - Z);
        if (g == 0) {
            ws[OFF_AEM + s] = we;
            ws[OFF_BDMA + s] = w0;
            ws[OFF_BDIA + s] = w1;
        } else {
            ws[OFF_AEI + s] = we;
            ws[OFF_BDMB + s] = w0;
            ws[OFF_BDIB + s] = w1;
        }
    }
    for (int j = tid; j < 385; j += nth) {
        ws[OFF_AW  + j] = (j <= 383) ? ews[j] : 1.0f;
        ws[OFF_BGM + j] = etmm[j];
        ws[OFF_BGI + j] = etii[j];
    }
    if (tid == 0) { ws[OFF_AEM+0] = 0.f; ws[OFF_BDMA+0] = 0.f; ws[OFF_BDIA+0] = 0.f; }
    // initial vector (raw)
    {
        float r000 = rn[0], r001 = rn[1];
        float u000 = un[0], u001 = un[1];
        for (int k = tid; k < 769; k += nth) {
            int g = (k < 384) ? 0 : 1;
            int m = (k < 384) ? k : (k - 384);
            float v;
            if (m == 0) v = g ? r001 : (r000 + u000);
            else {
                float tt = g ? ((m <= 383) ? rn[(m*3+2)*2+1] : 0.f)
                             : (rn[(m*3+2)*2+0] + un[(m*3+2)*2+0]);
                v = r000 + u001 - Cs[1] + Cs[m] + tt;
            }
            rawv[k] = v;
        }
    }
    __syncthreads();
    // block max via wave shuffles
    float lmax = -3.0e38f;
    for (int k = tid; k < 769; k += nth) lmax = fmaxf(lmax, rawv[k]);
    #pragma unroll
    for (int d = 1; d < 64; d <<= 1) lmax = fmaxf(lmax, __shfl_xor(lmax, d));
    if ((tid & 63) == 0) red[tid >> 6] = lmax;
    __syncthreads();
    float gmax = red[0];
    #pragma unroll
    for (int i = 1; i < 8; ++i) gmax = fmaxf(gmax, red[i]);
    float lsum = 0.f;
    for (int k = tid; k < 769; k += nth) lsum += expf(rawv[k] - gmax);
    #pragma unroll
    for (int d = 1; d < 64; d <<= 1) lsum += __shfl_xor(lsum, d);
    if ((tid & 63) == 0) red[8 + (tid >> 6)] = lsum;
    __syncthreads();
    float tsum = 0.f;
    #pragma unroll
    for (int i = 0; i < 8; ++i) tsum += red[8 + i];
    float lse = gmax + logf(tsum);
    for (int k = tid; k < 769; k += nth) {
        float p = expf(rawv[k] - lse);
        if (k < 384) ws[OFF_P0M + k] = p;
        else ws[OFF_P0I + (k-384)] = p;
    }
    if (tid == 0) ws[OFF_P0M + 384] = 0.f;
    // transposed lane-padded emission tables: zero then fill
    for (int i = tid; i < 10752; i += nth) { ws[OFF_WTM + i] = 0.f; ws[OFF_WTI + i] = 0.f; }
    __syncthreads();
    for (int row = tid; row < 769; row += nth) {
        const float* src = (row < 384) ? (ps + row*21) : (iseq + (row-384)*21);
        int j = (row < 384) ? row : (row - 384);
        float* dst = (row < 384) ? (ws + OFF_WTM) : (ws + OFF_WTI);
        float mx = -3.0e38f;
        for (int a = 0; a < 21; ++a) mx = fmaxf(mx, src[a]);
        float sm2 = 0.f;
        for (int a = 0; a < 21; ++a) sm2 += expf(src[a]-mx);
        float inv = 1.0f / sm2;
        int slot = (j/7)*8 + (j%7);
        for (int a = 0; a < 21; ++a) dst[a*512 + slot] = expf(src[a]-mx) * inv;
    }
}

__global__ __launch_bounds__(64, 1) void hmm_scan(const float* __restrict__ seq,
                                                  const float* __restrict__ ws,
                                                  const float* __restrict__ lscale,
                                                  float* __restrict__ out)
{
    const int b = blockIdx.x;
    const int lane = threadIdx.x;
    __shared__ int letters[256];
    const float* sb = seq + (size_t)b * 256 * 21;
    for (int c = 0; c < 4; ++c) {
        int t = c*64 + lane;
        const float* p = sb + t*21;
        float s = 0.f, wsum = 0.f;
        #pragma unroll
        for (int a = 0; a < 21; ++a) { float v = p[a]; s += v; wsum += v * (float)a; }
        letters[t] = (s > 0.5f) ? (int)(wsum + 0.5f) : -1;
    }
    __syncthreads();

    float c_em[7], c_ei[7], w[7], c_dma[7], c_dmb[7], c_gm[7], c_dia[7], c_dib[7], c_gi[7];
    float pm[7], pi[7];
    #pragma unroll
    for (int i = 0; i < 7; ++i) {
        int j = lane*7 + i;
        bool v = (j < 385);
        c_em[i]  = v ? ws[OFF_AEM  + j] : 0.f;
        c_ei[i]  = v ? ws[OFF_AEI  + j] : 0.f;
        w[i]     = v ? ws[OFF_AW   + j] : 1.f;
        c_dma[i] = v ? ws[OFF_BDMA + j] : 0.f;
        c_dmb[i] = v ? ws[OFF_BDMB + j] : 0.f;
        c_gm[i]  = v ? ws[OFF_BGM  + j] : 0.f;
        c_dia[i] = v ? ws[OFF_BDIA + j] : 0.f;
        c_dib[i] = v ? ws[OFF_BDIB + j] : 0.f;
        c_gi[i]  = v ? ws[OFF_BGI  + j] : 0.f;
        pm[i] = v ? ws[OFF_P0M + j] : 0.f;
        pi[i] = v ? ws[OFF_P0I + j] : 0.f;
    }
    // in-lane Kogge-Stone constants
    float pw[7];
    pw[0] = 1.f;
    #pragma unroll
    for (int i = 1; i < 7; ++i) pw[i] = pw[i-1] * w[i-1];
    const float W = pw[6] * w[6];
    const float A2_2 = w[2]*w[1], A2_3 = w[3]*w[2], A2_4 = w[4]*w[3], A2_5 = w[5]*w[4], A2_6 = w[6]*w[5];
    const float A4_4 = A2_4*A2_2, A4_5 = A2_5*A2_3, A4_6 = A2_6*A2_4;
    // wave-scan constants: window products of W (one-time shuffles OK here)
    float p = W;
    const float Ar0 = p;
    { float q = __shfl_up(p, 1); p *= q; }
    const float Ar1 = p;
    { float q = __shfl_up(p, 2); p *= q; }
    const float Ar2 = p;
    { float q = __shfl_up(p, 4); p *= q; }
    const float Ar3 = p;
    float prefR = W;
    #pragma unroll
    for (int d = 1; d < 16; d <<= 1) { float q = __shfl_up(prefR, d); if ((lane & 15) >= d) prefR *= q; }
    const int rw = lane >> 4;
    const float A15 = (rw == 1 || rw == 3) ? prefR : 0.f;
    const float s47 = __shfl(prefR, 47);
    const float A31 = (rw == 2) ? prefR : ((rw == 3) ? prefR * s47 : 0.f);

    const float* wtm = ws + OFF_WTM;
    const float* wti = ws + OFF_WTI;
    const int laneoff = lane * 8;

    { // t = 0 emission
        int lm = letters[0];
        if (lm >= 0) {
            const float4* em4 = (const float4*)(wtm + lm*512 + laneoff);
            const float4* ei4 = (const float4*)(wti + lm*512 + laneoff);
            float4 m0 = em4[0], m1 = em4[1], i0 = ei4[0], i1 = ei4[1];
            pm[0]*=m0.x; pm[1]*=m0.y; pm[2]*=m0.z; pm[3]*=m0.w; pm[4]*=m1.x; pm[5]*=m1.y; pm[6]*=m1.z;
            pi[0]*=i0.x; pi[1]*=i0.y; pi[2]*=i0.z; pi[3]*=i0.w; pi[4]*=i1.x; pi[5]*=i1.y; pi[6]*=i1.z;
        }
    }
    float logoff = 0.f;

    struct EmBuf { float m[8]; float ii[8]; bool has; };
    EmBuf Ab, Bb, Cb;
    auto loadbuf = [&](int lm, EmBuf& e) {
        int lmc = (lm < 0) ? 0 : lm;
        const float4* em4 = (const float4*)(wtm + lmc*512 + laneoff);
        const float4* ei4 = (const float4*)(wti + lmc*512 + laneoff);
        float4 a0 = em4[0], a1 = em4[1], b0 = ei4[0], b1 = ei4[1];
        e.m[0]=a0.x; e.m[1]=a0.y; e.m[2]=a0.z; e.m[3]=a0.w;
        e.m[4]=a1.x; e.m[5]=a1.y; e.m[6]=a1.z; e.m[7]=a1.w;
        e.ii[0]=b0.x; e.ii[1]=b0.y; e.ii[2]=b0.z; e.ii[3]=b0.w;
        e.ii[4]=b1.x; e.ii[5]=b1.y; e.ii[6]=b1.z; e.ii[7]=b1.w;
        e.has = (lm >= 0);
    };
    loadbuf(letters[1], Ab);
    loadbuf(letters[2], Bb);
    int l2 = letters[3], l3 = letters[4];

    auto step = [&](int t, EmBuf& cur, EmBuf& far) {
        // prefetch: letters 4 ahead, emissions 2 ahead
        int idx4 = t + 4; if (idx4 > 255) idx4 = 255;
        int l4 = letters[idx4];
        loadbuf(l2, far);
        l2 = l3; l3 = l4;
        // E' per position
        float ap[7];
        ap[0] = wshr1(pm[6], lane);
        #pragma unroll
        for (int i = 1; i < 7; ++i) ap[i] = pm[i-1];
        float E[7];
        #pragma unroll
        for (int i = 0; i < 7; ++i) E[i] = fmaf(pi[i], c_ei[i], ap[i]*c_em[i]);
        // Kogge-Stone in-lane inclusive weighted prefix (depth 3)
        float y1 = fmaf(w[1], E[0], E[1]);
        float y2 = fmaf(w[2], E[1], E[2]);
        float y3 = fmaf(w[3], E[2], E[3]);
        float y4 = fmaf(w[4], E[3], E[4]);
        float y5 = fmaf(w[5], E[4], E[5]);
        float y6 = fmaf(w[6], E[5], E[6]);
        float z2 = fmaf(A2_2, E[0], y2);
        float z3 = fmaf(A2_3, y1,   y3);
        float z4 = fmaf(A2_4, y2,   y4);
        float z5 = fmaf(A2_5, y3,   y5);
        float z6 = fmaf(A2_6, y4,   y6);
        float u4 = fmaf(A4_4, E[0], z4);
        float u5 = fmaf(A4_5, y1,   z5);
        float u6 = fmaf(A4_6, z2,   z6);
        // cross-lane weighted scan, all-DPP (segmented rows + bcast combine)
        float bb = u6;
        bb = fmaf(Ar0, fdpp<0x111>(bb), bb);
        bb = fmaf(Ar1, fdpp<0x112>(bb), bb);
        bb = fmaf(Ar2, fdpp<0x114>(bb), bb);
        bb = fmaf(Ar3, fdpp<0x118>(bb), bb);
        bb = fmaf(A15, fdpp<0x142>(bb), bb);
        bb = fmaf(A31, fdpp<0x143>(bb), bb);
        float bx = wshr1(bb, lane);
        // R[i] = pw[i]*bx + presum[i]
        float psum[7] = {0.f, E[0], y1, z2, z3, u4, u5};
        float R[7];
        R[0] = bx;
        #pragma unroll
        for (int i = 1; i < 7; ++i) R[i] = fmaf(pw[i], bx, psum[i]);
        // state update + emission
        #pragma unroll
        for (int i = 0; i < 7; ++i) {
            float t1 = fmaf(pi[i], c_dmb[i], ap[i]*c_dma[i]);
            float t2 = fmaf(pi[i], c_dib[i], ap[i]*c_dia[i]);
            float nm = fmaf(c_gm[i], R[i], t1);
            float ni = fmaf(c_gi[i], R[i], t2);
            if (cur.has) { nm *= cur.m[i]; ni *= cur.ii[i]; }
            pm[i] = nm; pi[i] = ni;
        }
        // renorm every 16 steps (all-DPP max reduce, values are >= 0)
        if ((t & 15) == 0) {
            float mx = 0.f;
            #pragma unroll
            for (int i = 0; i < 7; ++i) mx = fmaxf(mx, fmaxf(pm[i], pi[i]));
            mx = fmaxf(mx, fdpp<0x111>(mx));
            mx = fmaxf(mx, fdpp<0x112>(mx));
            mx = fmaxf(mx, fdpp<0x114>(mx));
            mx = fmaxf(mx, fdpp<0x118>(mx));
            mx = fmaxf(mx, fdpp<0x142>(mx));
            mx = fmaxf(mx, fdpp<0x143>(mx));
            float g = __shfl(mx, 63);
            if (g > 0.f) {
                float sc = 1.0f / g;
                logoff += logf(g);
                #pragma unroll
                for (int i = 0; i < 7; ++i) { pm[i] *= sc; pi[i] *= sc; }
            }
        }
    };

    for (int t = 1; t < 256; t += 3) {
        step(t,     Ab, Cb);
        step(t + 1, Bb, Ab);
        step(t + 2, Cb, Bb);
    }

    float s = 0.f;
    #pragma unroll
    for (int i = 0; i < 7; ++i) s += pm[i] + pi[i];
    #pragma unroll
    for (int d = 1; d < 64; d <<= 1) s += __shfl_xor(s, d);
    if (lane == 0) out[b] = lscale[0] * (logf(s) + logoff);
}

extern "C" void kernel_launch(void* const* d_in, const int* in_sizes, int n_in,
                              void* d_out, int out_size, void* d_ws, size_t ws_size,
                              hipStream_t stream)
{
    const float* ps   = (const float*)d_in[0];  // precursor_seq (384,21)
    const float* iseq = (const float*)d_in[1];  // insert_seq (385,21)
    const float* ins  = (const float*)d_in[2];  // insert (384,3,2)
    const float* del  = (const float*)d_in[3];  // delete (384,3,2)
    const float* seq  = (const float*)d_in[4];  // seq_data (64,256,21)
    const float* lsc  = (const float*)d_in[5];  // local_scale (1,)
    float* ws = (float*)d_ws;
    float* out = (float*)d_out;
    hmm_setup<<<1, 512, 0, stream>>>(ps, iseq, ins, del, ws);
    hmm_scan<<<64, 64, 0, stream>>>(seq, ws, lsc, out);
}

// Round 3
// 129.009 us; speedup vs baseline: 2.0706x; 1.2009x over previous
//
#include <hip/hip_runtime.h>
#include <hip/hip_bf16.h>

// ProfileHMM forward on MI355X.
// Reformulation: trans-matrix = diag-direct + rank-1-in-log-space delete chain;
// each scan step is a weighted prefix recurrence over 384 positions (+1 scalar
// special state I_M). One wave per batch element. Cross-lane via DPP; emission
// tables staged in LDS; float2 packed update (v_pk_fma_f32); runtime
// specialization: chain window-products >=2 lanes flush to exact fp32 zero for
// rare-indel data -> 1-round cross-lane scan (generic 6-round fallback kept).

#define NEGC (-1.0e32f)

// d_ws float offsets
#define OFF_AEM  0
#define OFF_AEI  385
#define OFF_AW   770
#define OFF_BDMA 1155
#define OFF_BDMB 1540
#define OFF_BGM  1925
#define OFF_BDIA 2310
#define OFF_BDIB 2695
#define OFF_BGI  3080
#define OFF_P0M  3465
#define OFF_P0I  3850
#define OFF_WT   4352            // [letter 21][lane 64][12] floats = 16128
#define OFF_EMS  (4352+16128)    // 64 floats: emS[21] for state I_M + pad
// total ws usage = 20544 floats = 82176 B

typedef float v2f __attribute__((ext_vector_type(2)));

#if __has_builtin(__builtin_elementwise_fma)
#define VFMA(a,b,c) __builtin_elementwise_fma((a),(b),(c))
#else
static __device__ __forceinline__ v2f VFMA(v2f a, v2f b, v2f c) {
    v2f r; r.x = fmaf(a.x,b.x,c.x); r.y = fmaf(a.y,b.y,c.y); return r;
}
#endif
#if __has_builtin(__builtin_elementwise_max)
#define VMAX(a,b) __builtin_elementwise_max((a),(b))
#else
static __device__ __forceinline__ v2f VMAX(v2f a, v2f b) {
    v2f r; r.x = fmaxf(a.x,b.x); r.y = fmaxf(a.y,b.y); return r;
}
#endif

static __device__ __forceinline__ v2f mkv2(float a, float b) { v2f r; r.x = a; r.y = b; return r; }

template<int CTRL>
__device__ __forceinline__ float fdpp(float x) {
    union { float f; int i; } u, r;
    u.f = x;
    r.i = __builtin_amdgcn_update_dpp(0, u.i, CTRL, 0xF, 0xF, true);
    return r.f;
}
// whole-wave shift right by 1 lane (lane0 <- 0): row_shr:1 + row_bcast15
__device__ __forceinline__ float wshr1(float x, int lane) {
    float a = fdpp<0x111>(x);
    float b = fdpp<0x142>(x);
    return ((lane & 15) == 0) ? b : a;
}
__device__ __forceinline__ float rdlane(float x, int l) {
    union { float f; int i; } u; u.f = x;
    u.i = __builtin_amdgcn_readlane(u.i, l);
    return u.f;
}

__global__ void hmm_setup(const float* __restrict__ ps, const float* __restrict__ iseq,
                          const float* __restrict__ rr, const float* __restrict__ uu,
                          float* __restrict__ ws)
{
    const int tid = threadIdx.x;
    const int nth = blockDim.x;   // 512
    __shared__ float rn[2304];
    __shared__ float un[2304];
    __shared__ float d2s[384];
    __shared__ float ews[385];
    __shared__ float etmm[385];
    __shared__ float etii[385];
    __shared__ float Cs[385];
    __shared__ float qa[385];
    __shared__ float rawv[769];
    __shared__ float red[16];

    for (int row = tid; row < 1152; row += nth) {
        float a = rr[row*2], b = rr[row*2+1];
        float mx = fmaxf(a, b);
        float l = mx + logf(expf(a-mx) + expf(b-mx));
        rn[row*2] = a - l; rn[row*2+1] = b - l;
        a = uu[row*2]; b = uu[row*2+1];
        mx = fmaxf(a, b);
        l = mx + logf(expf(a-mx) + expf(b-mx));
        un[row*2] = a - l; un[row*2+1] = b - l;
    }
    __syncthreads();
    for (int m = tid; m < 384; m += nth) {
        float d = rn[(m*3+2)*2+0] + un[(m*3+2)*2+1];
        d2s[m] = d;
        ews[m] = expf(d);
        etmm[m] = expf(rn[(m*3+2)*2+0] + un[(m*3+2)*2+0]);
        etii[m] = expf(rn[(m*3+2)*2+1]);
    }
    if (tid == 0) { ews[384] = 0.f; etmm[384] = 0.f; etii[384] = 1.f; }
    __syncthreads();
    if (tid < 64) {
        int lane = tid;
        float incl[6]; float z = 0.f;
        #pragma unroll
        for (int i = 0; i < 6; ++i) { z += d2s[lane*6+i]; incl[i] = z; }
        float tot = z;
        #pragma unroll
        for (int d = 1; d < 64; d <<= 1) { float q = __shfl_up(tot, d); if (lane >= d) tot += q; }
        float excl = __shfl_up(tot, 1); if (lane == 0) excl = 0.f;
        #pragma unroll
        for (int i = 0; i < 6; ++i) Cs[lane*6+i+1] = excl + incl[i];
        if (lane == 0) Cs[0] = 0.f;
    } else if (tid < 128) {
        int lane = tid - 64;
        float wv[6], xv[6], incl[6];
        #pragma unroll
        for (int i = 0; i < 6; ++i) {
            int s = 384 - (lane*6 + i);
            wv[i] = ews[s]; xv[i] = etii[s] + etmm[s];
        }
        float z = 0.f, Wl = 1.f;
        #pragma unroll
        for (int i = 0; i < 6; ++i) { z = fmaf(wv[i], z, xv[i]); incl[i] = z; Wl *= wv[i]; }
        float val = z, wt = Wl;
        #pragma unroll
        for (int d = 1; d < 64; d <<= 1) {
            float pv = __shfl_up(val, d); float pw_ = __shfl_up(wt, d);
            if (lane >= d) { val = fmaf(wt, pv, val); wt *= pw_; }
        }
        float excl = __shfl_up(val, 1); if (lane == 0) excl = 0.f;
        float pp = 1.f;
        #pragma unroll
        for (int i = 0; i < 6; ++i) {
            pp *= wv[i];
            float zf = fmaf(excl, pp, incl[i]);
            qa[383 - (lane*6 + i)] = zf;
        }
        if (lane == 0) qa[384] = 0.f;
    }
    __syncthreads();
    for (int k = tid; k < 769; k += nth) {
        int g = (k < 384) ? 0 : 1;
        int m = (k < 384) ? k : (k - 384);
        int s = m + 1 - g;
        float ss, sd, sm, si;
        if (s <= 383) {
            int base = (s*3 + g)*2;
            ss = rn[base+0]; si = rn[base+1];
            sm = un[base+0]; sd = un[base+1];
        } else { ss = NEGC; si = 0.f; sm = 0.f; sd = NEGC; }
        float d0 = (s <= 383) ? (ss + sm) : NEGC;
        float d1 = si;
        float q = qa[s];
        float lq = (q > 0.f) ? logf(q) : -1.0e30f;
        float ch = ss + sd + lq;
        float mx = fmaxf(fmaxf(d0, d1), ch);
        float Z = mx + logf(expf(d0-mx) + expf(d1-mx) + expf(ch-mx));
        float we = expf(ss + sd - Z);
        float w0 = expf(d0 - Z);
        float w1 = expf(d1 - Z);
        if (g == 0) {
            ws[OFF_AEM + s] = we;
            ws[OFF_BDMA + s] = w0;
            ws[OFF_BDIA + s] = w1;
        } else {
            ws[OFF_AEI + s] = we;
            ws[OFF_BDMB + s] = w0;
            ws[OFF_BDIB + s] = w1;
        }
    }
    for (int j = tid; j < 385; j += nth) {
        ws[OFF_AW  + j] = (j <= 383) ? ews[j] : 1.0f;
        ws[OFF_BGM + j] = etmm[j];
        ws[OFF_BGI + j] = etii[j];
    }
    if (tid == 0) { ws[OFF_AEM+0] = 0.f; ws[OFF_BDMA+0] = 0.f; ws[OFF_BDIA+0] = 0.f; }
    {
        float r000 = rn[0], r001 = rn[1];
        float u000 = un[0], u001 = un[1];
        for (int k = tid; k < 769; k += nth) {
            int g = (k < 384) ? 0 : 1;
            int m = (k < 384) ? k : (k - 384);
            float v;
            if (m == 0) v = g ? r001 : (r000 + u000);
            else {
                float tt = g ? ((m <= 383) ? rn[(m*3+2)*2+1] : 0.f)
                             : (rn[(m*3+2)*2+0] + un[(m*3+2)*2+0]);
                v = r000 + u001 - Cs[1] + Cs[m] + tt;
            }
            rawv[k] = v;
        }
    }
    __syncthreads();
    float lmax = -3.0e38f;
    for (int k = tid; k < 769; k += nth) lmax = fmaxf(lmax, rawv[k]);
    #pragma unroll
    for (int d = 1; d < 64; d <<= 1) lmax = fmaxf(lmax, __shfl_xor(lmax, d));
    if ((tid & 63) == 0) red[tid >> 6] = lmax;
    __syncthreads();
    float gmax = red[0];
    #pragma unroll
    for (int i = 1; i < 8; ++i) gmax = fmaxf(gmax, red[i]);
    float lsum = 0.f;
    for (int k = tid; k < 769; k += nth) lsum += expf(rawv[k] - gmax);
    #pragma unroll
    for (int d = 1; d < 64; d <<= 1) lsum += __shfl_xor(lsum, d);
    if ((tid & 63) == 0) red[8 + (tid >> 6)] = lsum;
    __syncthreads();
    float tsum = 0.f;
    #pragma unroll
    for (int i = 0; i < 8; ++i) tsum += red[8 + i];
    float lse = gmax + logf(tsum);
    for (int k = tid; k < 769; k += nth) {
        float p = expf(rawv[k] - lse);
        if (k < 384) ws[OFF_P0M + k] = p;
        else ws[OFF_P0I + (k-384)] = p;
    }
    if (tid == 0) ws[OFF_P0M + 384] = 0.f;
    // emission tables: [letter][lane][12] (slots 0-5 match j=lane*6+k, 6-11 insert) + emS row
    for (int row = tid; row < 769; row += nth) {
        const float* src = (row < 384) ? (ps + row*21) : (iseq + (row-384)*21);
        float mx = -3.0e38f;
        for (int a = 0; a < 21; ++a) mx = fmaxf(mx, src[a]);
        float sm2 = 0.f;
        for (int a = 0; a < 21; ++a) sm2 += expf(src[a]-mx);
        float inv = 1.0f / sm2;
        if (row < 384) {
            int l = row/6, k = row%6;
            float* dst = ws + OFF_WT + l*12 + k;
            for (int a = 0; a < 21; ++a) dst[a*768] = expf(src[a]-mx)*inv;
        } else if (row < 768) {
            int j = row - 384;
            int l = j/6, k = j%6;
            float* dst = ws + OFF_WT + l*12 + 6 + k;
            for (int a = 0; a < 21; ++a) dst[a*768] = expf(src[a]-mx)*inv;
        } else {
            for (int a = 0; a < 21; ++a) ws[OFF_EMS + a] = expf(src[a]-mx)*inv;
            for (int a = 21; a < 64; ++a) ws[OFF_EMS + a] = 0.f;
        }
    }
}

#define RENORM do { \
    v2f mv = VMAX(VMAX(Pm0,Pm1), VMAX(Pm2, VMAX(Pi0, VMAX(Pi1,Pi2)))); \
    float mxr = fmaxf(mv.x, mv.y); \
    mxr = fmaxf(mxr, fdpp<0x111>(mxr)); \
    mxr = fmaxf(mxr, fdpp<0x112>(mxr)); \
    mxr = fmaxf(mxr, fdpp<0x114>(mxr)); \
    mxr = fmaxf(mxr, fdpp<0x118>(mxr)); \
    mxr = fmaxf(mxr, fdpp<0x142>(mxr)); \
    mxr = fmaxf(mxr, fdpp<0x143>(mxr)); \
    float g = fmaxf(rdlane(mxr, 63), pi384); \
    if (g > 0.f) { \
        float sc = 0x1p50f / g; \
        logoff += logf(g) - 34.65735902799726547f; \
        Pm0 *= sc; Pm1 *= sc; Pm2 *= sc; Pi0 *= sc; Pi1 *= sc; Pi2 *= sc; pi384 *= sc; \
    } \
} while (0)

#define STEP(FAST, CUR, FAR, T) do { \
    { int lmv = lN2; lN2 = lN3; int ti = (T)+4; ti = ti > 255 ? 255 : ti; lN3 = (int)lets[ti]; fill(lmv, FAR); } \
    float apx = wshr1(Pm2.y, lane); \
    float pm383o = rdlane(Pm2.y, 63); \
    v2f Ap0 = mkv2(apx, Pm0.x), Ap1 = mkv2(Pm0.y, Pm1.x), Ap2 = mkv2(Pm1.y, Pm2.x); \
    v2f E0 = VFMA(Pi0, Cei0, Ap0*Cem0); \
    v2f E1 = VFMA(Pi1, Cei1, Ap1*Cem1); \
    v2f E2 = VFMA(Pi2, Cei2, Ap2*Cem2); \
    float i0 = E0.x; \
    float i1 = fmaf(w1, i0, E0.y); \
    float i2 = fmaf(w2, i1, E1.x); \
    float i3 = fmaf(w3, i2, E1.y); \
    float i4 = fmaf(w4, i3, E2.x); \
    float i5 = fmaf(w5, i4, E2.y); \
    float bb = i5; \
    if (FAST) { bb = fmaf(Ar0, wshr1(bb, lane), bb); } \
    else { \
        bb = fmaf(Ar0, fdpp<0x111>(bb), bb); \
        bb = fmaf(Ar1, fdpp<0x112>(bb), bb); \
        bb = fmaf(Ar2, fdpp<0x114>(bb), bb); \
        bb = fmaf(Ar3, fdpp<0x118>(bb), bb); \
        bb = fmaf(A15, fdpp<0x142>(bb), bb); \
        bb = fmaf(A31, fdpp<0x143>(bb), bb); \
    } \
    float R384 = rdlane(bb, 63); \
    float bx = wshr1(bb, lane); \
    v2f Rv0 = mkv2(bx, fmaf(pw1, bx, i0)); \
    v2f Rv1 = mkv2(fmaf(pw2, bx, i1), fmaf(pw3, bx, i2)); \
    v2f Rv2 = mkv2(fmaf(pw4, bx, i3), fmaf(pw5, bx, i4)); \
    v2f nm0 = VFMA(Cgm0, Rv0, VFMA(Pi0, Cdmb0, Ap0*Cdma0)); \
    v2f nm1 = VFMA(Cgm1, Rv1, VFMA(Pi1, Cdmb1, Ap1*Cdma1)); \
    v2f nm2 = VFMA(Cgm2, Rv2, VFMA(Pi2, Cdmb2, Ap2*Cdma2)); \
    v2f ni0 = VFMA(Cgi0, Rv0, VFMA(Pi0, Cdib0, Ap0*Cdia0)); \
    v2f ni1 = VFMA(Cgi1, Rv1, VFMA(Pi1, Cdib1, Ap1*Cdia1)); \
    v2f ni2 = VFMA(Cgi2, Rv2, VFMA(Pi2, Cdib2, Ap2*Cdia2)); \
    float np384 = fmaf(pm383o, sDia, fmaf(pi384, sDib, sGi*R384)); \
    if (CUR.has) { \
        nm0 *= CUR.em0; nm1 *= CUR.em1; nm2 *= CUR.em2; \
        ni0 *= CUR.ei0; ni1 *= CUR.ei1; ni2 *= CUR.ei2; \
        np384 *= CUR.es; \
    } \
    Pm0 = nm0; Pm1 = nm1; Pm2 = nm2; Pi0 = ni0; Pi1 = ni1; Pi2 = ni2; pi384 = np384; \
    if (((T) & 15) == 0) { RENORM; } \
} while (0)

__global__ __launch_bounds__(64, 1) void hmm_scan(const float* __restrict__ seq,
                                                  const float* __restrict__ ws,
                                                  const float* __restrict__ lscale,
                                                  float* __restrict__ out)
{
    __shared__ float4 smem4[4064];               // 65024 B
    float* smem = (float*)smem4;
    unsigned char* lets = (unsigned char*)smem + 64768;
    const int b = blockIdx.x;
    const int lane = threadIdx.x;

    // stage emission tables global -> LDS (64768 B: WT 64512 + emS 256)
    const float4* srcT = (const float4*)(ws + OFF_WT);
    for (int i = 0; i < 63; ++i) smem4[i*64 + lane] = srcT[i*64 + lane];
    if (lane < 16) smem4[63*64 + lane] = srcT[63*64 + lane];

    // letters (argmax of one-hot; 21 = missing)
    const float* sb = seq + (size_t)b * 256 * 21;
    for (int c = 0; c < 4; ++c) {
        int t = c*64 + lane;
        const float* p = sb + t*21;
        float s = 0.f, wsum = 0.f;
        #pragma unroll
        for (int a = 0; a < 21; ++a) { float v = p[a]; s += v; wsum += v*(float)a; }
        lets[t] = (s > 0.5f) ? (unsigned char)(int)(wsum + 0.5f) : (unsigned char)21;
    }

    // per-lane coefficients (positions j = lane*6 + 0..5)
    const int j0 = lane*6;
    v2f Cem0,Cem1,Cem2, Cei0,Cei1,Cei2, Cdma0,Cdma1,Cdma2, Cdmb0,Cdmb1,Cdmb2;
    v2f Cgm0,Cgm1,Cgm2, Cdia0,Cdia1,Cdia2, Cdib0,Cdib1,Cdib2, Cgi0,Cgi1,Cgi2;
    v2f Pm0,Pm1,Pm2, Pi0,Pi1,Pi2;
    float w1,w2,w3,w4,w5, W0;
    {
        const float* p;
        p = ws+OFF_AEM+j0;  Cem0=mkv2(p[0],p[1]); Cem1=mkv2(p[2],p[3]); Cem2=mkv2(p[4],p[5]);
        p = ws+OFF_AEI+j0;  Cei0=mkv2(p[0],p[1]); Cei1=mkv2(p[2],p[3]); Cei2=mkv2(p[4],p[5]);
        p = ws+OFF_BDMA+j0; Cdma0=mkv2(p[0],p[1]); Cdma1=mkv2(p[2],p[3]); Cdma2=mkv2(p[4],p[5]);
        p = ws+OFF_BDMB+j0; Cdmb0=mkv2(p[0],p[1]); Cdmb1=mkv2(p[2],p[3]); Cdmb2=mkv2(p[4],p[5]);
        p = ws+OFF_BGM+j0;  Cgm0=mkv2(p[0],p[1]); Cgm1=mkv2(p[2],p[3]); Cgm2=mkv2(p[4],p[5]);
        p = ws+OFF_BDIA+j0; Cdia0=mkv2(p[0],p[1]); Cdia1=mkv2(p[2],p[3]); Cdia2=mkv2(p[4],p[5]);
        p = ws+OFF_BDIB+j0; Cdib0=mkv2(p[0],p[1]); Cdib1=mkv2(p[2],p[3]); Cdib2=mkv2(p[4],p[5]);
        p = ws+OFF_BGI+j0;  Cgi0=mkv2(p[0],p[1]); Cgi1=mkv2(p[2],p[3]); Cgi2=mkv2(p[4],p[5]);
        p = ws+OFF_P0M+j0;  Pm0=mkv2(p[0],p[1]); Pm1=mkv2(p[2],p[3]); Pm2=mkv2(p[4],p[5]);
        p = ws+OFF_P0I+j0;  Pi0=mkv2(p[0],p[1]); Pi1=mkv2(p[2],p[3]); Pi2=mkv2(p[4],p[5]);
        p = ws+OFF_AW+j0;   W0=p[0]; w1=p[1]; w2=p[2]; w3=p[3]; w4=p[4]; w5=p[5];
    }
    const float sDia = ws[OFF_BDIA+384], sDib = ws[OFF_BDIB+384], sGi = ws[OFF_BGI+384];
    float pi384 = ws[OFF_P0I+384];
    const float pw1 = W0, pw2 = pw1*w1, pw3 = pw2*w2, pw4 = pw3*w3, pw5 = pw4*w4;
    const float W = pw5*w5;
    // cross-lane window products (init-time shuffles are fine)
    float p_ = W;
    const float Ar0 = p_;
    { float q = __shfl_up(p_, 1); p_ *= q; } const float Ar1 = p_;
    { float q = __shfl_up(p_, 2); p_ *= q; } const float Ar2 = p_;
    { float q = __shfl_up(p_, 4); p_ *= q; } const float Ar3 = p_;
    float prefR = W;
    #pragma unroll
    for (int d = 1; d < 16; d <<= 1) { float q = __shfl_up(prefR, d); if ((lane & 15) >= d) prefR *= q; }
    const int rw = lane >> 4;
    const float A15 = (rw == 1 || rw == 3) ? prefR : 0.f;
    const float s47 = __shfl(prefR, 47);
    const float A31 = (rw == 2) ? prefR : ((rw == 3) ? prefR * s47 : 0.f);
    // fast iff every multiplier reaching distance >= 2 lanes is exactly 0
    bool bad = (Ar1 != 0.f) || (Ar2 != 0.f) || (Ar3 != 0.f)
             || ((A15 != 0.f) && ((lane & 15) >= 1))
             || ((A31 != 0.f) && (lane >= 33));
    const bool fastAll = (__ballot(bad) == 0ull);

    __syncthreads();

    float logoff = 0.f;
    {   // t = 0 emission + initial renorm to 2^50
        int lm = __builtin_amdgcn_readfirstlane((int)lets[0]);
        if (lm != 21) {
            const float* base = smem + lm*768 + lane*12;
            float4 q0 = *(const float4*)(base), q1 = *(const float4*)(base+4), q2 = *(const float4*)(base+8);
            Pm0 *= mkv2(q0.x,q0.y); Pm1 *= mkv2(q0.z,q0.w); Pm2 *= mkv2(q1.x,q1.y);
            Pi0 *= mkv2(q1.z,q1.w); Pi1 *= mkv2(q2.x,q2.y); Pi2 *= mkv2(q2.z,q2.w);
            pi384 *= smem[16128 + lm];
        }
        RENORM;
    }

    struct Buf { v2f em0, em1, em2, ei0, ei1, ei2; float es; bool has; };
    Buf bA, bB, bC;
    auto fill = [&](int lmv, Buf& e) {
        int lm = __builtin_amdgcn_readfirstlane(lmv);
        e.has = (lm != 21);
        if (e.has) {
            const float* base = smem + lm*768 + lane*12;
            float4 q0 = *(const float4*)(base), q1 = *(const float4*)(base+4), q2 = *(const float4*)(base+8);
            e.em0 = mkv2(q0.x,q0.y); e.em1 = mkv2(q0.z,q0.w); e.em2 = mkv2(q1.x,q1.y);
            e.ei0 = mkv2(q1.z,q1.w); e.ei1 = mkv2(q2.x,q2.y); e.ei2 = mkv2(q2.z,q2.w);
            e.es = smem[16128 + lm];
        }
    };
    fill((int)lets[1], bA);
    fill((int)lets[2], bB);
    int lN2 = (int)lets[3], lN3 = (int)lets[4];

    if (fastAll) {
        for (int t = 1; t < 256; t += 3) {
            STEP(1, bA, bC, t);
            STEP(1, bB, bA, t+1);
            STEP(1, bC, bB, t+2);
        }
    } else {
        for (int t = 1; t < 256; t += 3) {
            STEP(0, bA, bC, t);
            STEP(0, bB, bA, t+1);
            STEP(0, bC, bB, t+2);
        }
    }

    v2f sv = Pm0 + Pm1 + Pm2 + Pi0 + Pi1 + Pi2;
    float s = sv.x + sv.y;
    s += fdpp<0x111>(s); s += fdpp<0x112>(s); s += fdpp<0x114>(s); s += fdpp<0x118>(s);
    s += fdpp<0x142>(s); s += fdpp<0x143>(s);
    float stot = rdlane(s, 63) + pi384;
    if (lane == 0) out[b] = lscale[0] * (logf(stot) + logoff);
}

extern "C" void kernel_launch(void* const* d_in, const int* in_sizes, int n_in,
                              void* d_out, int out_size, void* d_ws, size_t ws_size,
                              hipStream_t stream)
{
    const float* ps   = (const float*)d_in[0];  // precursor_seq (384,21)
    const float* iseq = (const float*)d_in[1];  // insert_seq (385,21)
    const float* ins  = (const float*)d_in[2];  // insert (384,3,2)
    const float* del  = (const float*)d_in[3];  // delete (384,3,2)
    const float* seq  = (const float*)d_in[4];  // seq_data (64,256,21)
    const float* lsc  = (const float*)d_in[5];  // local_scale (1,)
    float* ws = (float*)d_ws;
    float* out = (float*)d_out;
    hmm_setup<<<1, 512, 0, stream>>>(ps, iseq, ins, del, ws);
    hmm_scan<<<64, 64, 0, stream>>>(seq, ws, lsc, out);
}